// Round 7
// baseline (292.266 us; speedup 1.0000x reference)
//
#include <hip/hip_runtime.h>
#include <stdint.h>
#include <math.h>

#define S_LEN 2048
#define DMODEL 1024
#define NHEAD 16
#define DHEAD 64
#define BATCH 4
#define MROWS (BATCH * S_LEN) // 8192

typedef __attribute__((ext_vector_type(8))) short bf16x8;
typedef __attribute__((ext_vector_type(4))) float f32x4;

#define MFMA16(a, b, c) __builtin_amdgcn_mfma_f32_16x16x32_bf16(a, b, c, 0, 0, 0)

__device__ __forceinline__ unsigned short f2b(float f) {
  union { float f; unsigned u; } v; v.f = f;
  unsigned u = v.u;
  return (unsigned short)((u + 0x7FFFu + ((u >> 16) & 1u)) >> 16);
}
// pack two f32 -> bf16x2 in ONE VALU op (RNE); replaces 3-op pkrn. lo=a, hi=b.
__device__ __forceinline__ unsigned cvtpk(float a, float b) {
  unsigned r;
  asm("v_cvt_pk_bf16_f32 %0, %1, %2" : "=v"(r) : "v"(a), "v"(b));
  return r;
}
// bare v_exp_f32 (2^x), ~1 ulp: skip any libm fixup path
#define EXP2F(x) __builtin_amdgcn_exp2f(x)

// async global->LDS, 16B per lane; LDS dest = uniform base + lane*16
__device__ __forceinline__ void async16(const void* g, void* l) {
  __builtin_amdgcn_global_load_lds((const __attribute__((address_space(1))) void*)g,
                                   (__attribute__((address_space(3))) void*)l,
                                   16, 0, 0);
}

// ---------------- fused prep: f32->bf16 cvt (Xb) + 4x 1024x1024 transpose ---
struct PrepArgs {
  const float4* x; unsigned short* xb; int n4; int cvtBlocks;
  const float* s[4]; unsigned short* d[4];
};
__global__ __launch_bounds__(256) void prep_kernel(PrepArgs p) {
  __shared__ float T[64][65];
  const int bid = blockIdx.x;
  const int t = threadIdx.x;
  if (bid < p.cvtBlocks) {
    int i = bid * 256 + t;
    if (i < p.n4) {
      float4 v = p.x[i];
      ushort4 o;
      o.x = f2b(v.x); o.y = f2b(v.y); o.z = f2b(v.z); o.w = f2b(v.w);
      *(ushort4*)(p.xb + 4 * (size_t)i) = o;
    }
    return;
  }
  const int tb = bid - p.cvtBlocks;
  const int z = tb >> 8;
  const int rem = tb & 255;
  const int r0 = (rem >> 4) * 64, c0 = (rem & 15) * 64;
  const float* in = p.s[z];
  unsigned short* out = p.d[z];
  int c = t & 63, rr = t >> 6;
#pragma unroll
  for (int i = 0; i < 16; i++) {
    int r = i * 4 + rr;
    T[r][c] = in[(size_t)(r0 + r) * 1024 + c0 + c];
  }
  __syncthreads();
  int r2 = t & 63, cc = t >> 6;
#pragma unroll
  for (int i = 0; i < 16; i++) {
    int c2 = i * 4 + cc;
    out[(size_t)(c0 + c2) * 1024 + r0 + r2] = f2b(T[r2][c2]);
  }
}

// ---------------- fused QKV GEMM: C[8192,3072] = Xb * Wqkv^T -----------------
// PROVEN 128^2 2-barrier structure (72.8us, 708 TF, MfmaUtil 29).
// R3's 256^2 8-phase port REGRESSED to 92us; needs the exact HK
// barrier/residency placement (m152) -- do not re-attempt naively.
__global__ __launch_bounds__(256) void gemm_qkv(const unsigned short* __restrict__ A,
                                                const unsigned short* __restrict__ Bt,
                                                unsigned short* __restrict__ Qr,
                                                unsigned short* __restrict__ Kr,
                                                unsigned short* __restrict__ Vt,
                                                const int* __restrict__ pos) {
  constexpr int K = 1024;
  __shared__ unsigned short As[128 * 64];
  __shared__ unsigned short Bs[128 * 64];
  const int bm = blockIdx.y * 128, bn = blockIdx.x * 128;
  const int t = threadIdx.x;
  const int wave = t >> 6, lane = t & 63, quad = lane >> 4, l16 = lane & 15;
  const int wm = (wave >> 1) * 64, wn = (wave & 1) * 64;
  f32x4 acc[4][4] = {};
  const int srow = lane >> 3;
  const int gcol = (((lane & 7) ^ srow)) * 8; // XOR-swizzled source column
  const unsigned short* Ag = A + (size_t)(bm + wave * 32 + srow) * K + gcol;
  const unsigned short* Bg = Bt + (size_t)(bn + wave * 32 + srow) * K + gcol;
  unsigned short* AsW = &As[(wave * 32) * 64];
  unsigned short* BsW = &Bs[(wave * 32) * 64];
  const int rsw = l16 & 7;

  for (int k0 = 0; k0 < K; k0 += 64) {
    __syncthreads();
#pragma unroll
    for (int i = 0; i < 4; i++) {
      async16(Ag + (size_t)(i * 8) * K + k0, AsW + i * 8 * 64);
      async16(Bg + (size_t)(i * 8) * K + k0, BsW + i * 8 * 64);
    }
    __syncthreads();
#pragma unroll
    for (int kk = 0; kk < 2; kk++) {
      const int sl = ((kk * 4 + quad) ^ rsw) << 3;
      bf16x8 af[4], bfr[4];
#pragma unroll
      for (int mt = 0; mt < 4; mt++)
        af[mt] = *(const bf16x8*)&As[(wm + mt * 16 + l16) * 64 + sl];
#pragma unroll
      for (int nt = 0; nt < 4; nt++)
        bfr[nt] = *(const bf16x8*)&Bs[(wn + nt * 16 + l16) * 64 + sl];
#pragma unroll
      for (int mt = 0; mt < 4; mt++)
#pragma unroll
        for (int nt = 0; nt < 4; nt++)
          acc[mt][nt] = MFMA16(af[mt], bfr[nt], acc[mt][nt]);
    }
  }

  const int cb = bn + wn;
  if (cb >= 2048) {
    // V: write directly transposed [b,h,dh,s]
    const int h = (cb - 2048) >> 6;
#pragma unroll
    for (int mt = 0; mt < 4; mt++)
#pragma unroll
      for (int nt = 0; nt < 4; nt++) {
        int row = bm + wm + mt * 16 + quad * 4;
        int b = row >> 11, s = row & (S_LEN - 1);
        int dh = nt * 16 + l16;
        ushort4 w4;
        w4.x = f2b(acc[mt][nt][0]); w4.y = f2b(acc[mt][nt][1]);
        w4.z = f2b(acc[mt][nt][2]); w4.w = f2b(acc[mt][nt][3]);
        *(ushort4*)&Vt[((size_t)(b * NHEAD + h) * DHEAD + dh) * S_LEN + s] = w4;
      }
  } else {
    const bool isQ = cb < 1024;
    unsigned short* dst0 = isQ ? Qr : Kr;
    const float scl = isQ ? 0.18033688011112042f : 1.0f; // 0.125*log2(e) for Q
    const int h = (cb >> 6) & 15;
    const float LT = 0.28782313662425572f; // ln(10000)/32
    float it0 = __expf(-(float)l16 * LT);
    float it1 = __expf(-(float)(16 + l16) * LT);
#pragma unroll
    for (int mt = 0; mt < 4; mt++) {
#pragma unroll
      for (int r = 0; r < 4; r++) {
        int row = bm + wm + mt * 16 + quad * 4 + r;
        int b = row >> 11, s = row & (S_LEN - 1);
        float p = (float)pos[row];
        // fast HW sin/cos: arg<=2047 rad, reduction error ~1e-4 << bf16
        // storage error. libm sincosf cost ~= the whole MFMA loop (R6).
        float a0 = p * it0, a1 = p * it1;
        float sn0 = __sinf(a0), cs0 = __cosf(a0);
        float sn1 = __sinf(a1), cs1 = __cosf(a1);
        float x0 = acc[mt][0][r], x1 = acc[mt][1][r];
        float x2 = acc[mt][2][r], x3 = acc[mt][3][r];
        float o0 = (x0 * cs0 - x2 * sn0) * scl;
        float o2 = (x2 * cs0 + x0 * sn0) * scl;
        float o1 = (x1 * cs1 - x3 * sn1) * scl;
        float o3 = (x3 * cs1 + x1 * sn1) * scl;
        unsigned short* dst =
            dst0 + ((size_t)(b * NHEAD + h) * S_LEN + s) * DHEAD;
        dst[0 * 16 + l16] = f2b(o0);
        dst[1 * 16 + l16] = f2b(o1);
        dst[2 * 16 + l16] = f2b(o2);
        dst[3 * 16 + l16] = f2b(o3);
      }
    }
  }
}

// ---------------- out-proj GEMM: out[8192,1024] f32 = Xat * WoT^T -----------
__global__ __launch_bounds__(256) void gemm_out(const unsigned short* __restrict__ A,
                                                const unsigned short* __restrict__ Bt,
                                                float* __restrict__ C) {
  constexpr int K = 1024, N = 1024;
  __shared__ unsigned short As[128 * 64];
  __shared__ unsigned short Bs[128 * 64];
  const int bm = blockIdx.y * 128, bn = blockIdx.x * 128;
  const int t = threadIdx.x;
  const int wave = t >> 6, lane = t & 63, quad = lane >> 4, l16 = lane & 15;
  const int wm = (wave >> 1) * 64, wn = (wave & 1) * 64;
  f32x4 acc[4][4] = {};
  const int srow = lane >> 3;
  const int gcol = (((lane & 7) ^ srow)) * 8;
  const unsigned short* Ag = A + (size_t)(bm + wave * 32 + srow) * K + gcol;
  const unsigned short* Bg = Bt + (size_t)(bn + wave * 32 + srow) * K + gcol;
  unsigned short* AsW = &As[(wave * 32) * 64];
  unsigned short* BsW = &Bs[(wave * 32) * 64];
  const int rsw = l16 & 7;

  for (int k0 = 0; k0 < K; k0 += 64) {
    __syncthreads();
#pragma unroll
    for (int i = 0; i < 4; i++) {
      async16(Ag + (size_t)(i * 8) * K + k0, AsW + i * 8 * 64);
      async16(Bg + (size_t)(i * 8) * K + k0, BsW + i * 8 * 64);
    }
    __syncthreads();
#pragma unroll
    for (int kk = 0; kk < 2; kk++) {
      const int sl = ((kk * 4 + quad) ^ rsw) << 3;
      bf16x8 af[4], bfr[4];
#pragma unroll
      for (int mt = 0; mt < 4; mt++)
        af[mt] = *(const bf16x8*)&As[(wm + mt * 16 + l16) * 64 + sl];
#pragma unroll
      for (int nt = 0; nt < 4; nt++)
        bfr[nt] = *(const bf16x8*)&Bs[(wn + nt * 16 + l16) * 64 + sl];
#pragma unroll
      for (int mt = 0; mt < 4; mt++)
#pragma unroll
        for (int nt = 0; nt < 4; nt++)
          acc[mt][nt] = MFMA16(af[mt], bfr[nt], acc[mt][nt]);
    }
  }
#pragma unroll
  for (int mt = 0; mt < 4; mt++)
#pragma unroll
    for (int nt = 0; nt < 4; nt++)
#pragma unroll
      for (int r = 0; r < 4; r++) {
        int row = bm + wm + mt * 16 + quad * 4 + r;
        int col = bn + wn + nt * 16 + l16;
        C[(size_t)row * N + col] = acc[mt][nt][r];
      }
}

// ---------------- flash attention: 128 q-rows/block (two 64-row halves) -----
// STALL-DOMINATED (R6 analysis): per-SIMD countable issue ~15us vs 65us wall;
// LDS-read trim (R6) bought ~1us while VALU-chain trim (R5) bought 7us ->
// serial QK->exp->pack->PV chain + per-tile barrier drains dominate, hidden
// by only 3 chains/SIMD. R7: occupancy 3->4 blocks/CU. LDS 40KB x 4 = exactly
// the 160KB pool; VGPR ~116 < 128 cap at waves/EU=4; grid 1024 = exactly
// 4x256 CUs. One more independent chain per SIMD (+33% latency hiding).
// exp2f -> __builtin_amdgcn_exp2f: bare v_exp_f32 (likely null per m214 v48,
// included to remove the libm confound).
__global__ __launch_bounds__(256, 4) void flash_kernel(const unsigned short* __restrict__ Qr,
                                                       const unsigned short* __restrict__ Kr,
                                                       const unsigned short* __restrict__ Vt,
                                                       unsigned short* __restrict__ Xat) {
  const int idx = blockIdx.x;        // 0..1023
  const int j = idx >> 6;            // 0..15
  const int c = j & 3, kcl = j >> 2;
  const int qt = (kcl == 0) ? 15 - c : (kcl == 1) ? 7 - c : (kcl == 2) ? 8 + c : c;
  const int bh = idx & 63;
  const unsigned short* Qh = Qr + (size_t)bh * S_LEN * DHEAD;
  const unsigned short* Kh = Kr + (size_t)bh * S_LEN * DHEAD;
  const unsigned short* Vh = Vt + (size_t)bh * DHEAD * S_LEN;
  __shared__ unsigned short Ks[2][64 * 64]; // [kcol][dh], XOR-swizzled slots
  __shared__ unsigned short Vs[2][64 * 64]; // [dh][kcol], XOR-swizzled slots
  __shared__ unsigned short Pt[4][16 * 64]; // per-wave P^T [q][k], swizzled
  const int t = threadIdx.x, wave = t >> 6, lane = t & 63;
  const int quad = lane >> 4, l16 = lane & 15;
  const int srow = lane >> 3;
  const int gcol = (((lane & 7) ^ srow)) * 8;
  const int rsw = l16 & 7;
  const int q0 = qt * 128;
  const int qrA = q0 + wave * 16 + l16;  // half A row
  const int qrB = qrA + 64;              // half B row

  bf16x8 qfA0 = *(const bf16x8*)(Qh + (size_t)qrA * DHEAD + quad * 8);
  bf16x8 qfA1 = *(const bf16x8*)(Qh + (size_t)qrA * DHEAD + 32 + quad * 8);
  bf16x8 qfB0 = *(const bf16x8*)(Qh + (size_t)qrB * DHEAD + quad * 8);
  bf16x8 qfB1 = *(const bf16x8*)(Qh + (size_t)qrB * DHEAD + 32 + quad * 8);

  f32x4 oA[4] = {}, oB[4] = {};
  f32x4 lsA = {}, lsB = {};  // row-sum accumulators (ones-MFMA); lane's q=l16
  bf16x8 onesf;
#pragma unroll
  for (int i = 0; i < 8; i++) onesf[i] = (short)0x3F80; // bf16 1.0
  unsigned short* PtW = &Pt[wave][0];
  const int c0 = (quad ^ rsw) << 3;        // kk=0 frag slot
  const int c1 = ((4 + quad) ^ rsw) << 3;  // kk=1 frag slot
  const int q1b = quad >> 1, qlo4 = (quad & 1) * 4;
  const int pr = l16 * 64;

  auto stage = [&](int kt, int buf) {
    const int k0 = kt * 64;
#pragma unroll
    for (int i = 0; i < 2; i++) {
      async16(Kh + (size_t)(k0 + wave * 16 + i * 8 + srow) * DHEAD + gcol,
              &Ks[buf][(wave * 16 + i * 8) * 64]);
      async16(Vh + (size_t)(wave * 16 + i * 8 + srow) * S_LEN + k0 + gcol,
              &Vs[buf][(wave * 16 + i * 8) * 64]);
    }
  };

  // softmax (no running max: scores bounded) + P^T pack + PV accumulate.
  // V-frags passed in registers (shared across both halves).
  // Row-sum l via ones-MFMA: lane's col = l16 = its q.
  auto softpv = [&](const bf16x8* vb0, const bf16x8* vb1, f32x4* sc, f32x4* o,
                    f32x4& ls, int qr_, bool diag, int k0) {
#pragma unroll
    for (int nt = 0; nt < 4; nt++) {
      float p0, p1, p2, p3;
      if (diag) {
        int kg = k0 + nt * 16 + quad * 4;
        p0 = (kg + 0 > qr_) ? 0.f : EXP2F(sc[nt][0]);
        p1 = (kg + 1 > qr_) ? 0.f : EXP2F(sc[nt][1]);
        p2 = (kg + 2 > qr_) ? 0.f : EXP2F(sc[nt][2]);
        p3 = (kg + 3 > qr_) ? 0.f : EXP2F(sc[nt][3]);
      } else {
        p0 = EXP2F(sc[nt][0]);
        p1 = EXP2F(sc[nt][1]);
        p2 = EXP2F(sc[nt][2]);
        p3 = EXP2F(sc[nt][3]);
      }
      uint2 w; w.x = cvtpk(p0, p1); w.y = cvtpk(p2, p3);
      const int slot = ((nt * 2 + q1b) ^ rsw) << 3; // nt literal; XOR != dist over +
      *(uint2*)&PtW[pr + slot + qlo4] = w;
    }
#pragma unroll
    for (int kk = 0; kk < 2; kk++) {
      bf16x8 pb = *(const bf16x8*)&PtW[pr + (((kk * 4 + quad) ^ rsw) << 3)];
      ls = MFMA16(onesf, pb, ls);
      const bf16x8* vb = (kk == 0) ? vb0 : vb1; // kk literal under unroll
#pragma unroll
      for (int nt = 0; nt < 4; nt++) o[nt] = MFMA16(vb[nt], pb, o[nt]);
    }
  };

  // both halves against one tile; K-frags AND V-frags read once from LDS
  auto computeAB = [&](int cur, int k0, bool adiag) {
    const unsigned short* K_ = Ks[cur];
    const unsigned short* V_ = Vs[cur];
    f32x4 scA[4] = {}, scB[4] = {};
    bf16x8 vb0[4], vb1[4];
#pragma unroll
    for (int nt = 0; nt < 4; nt++) {
      bf16x8 kb0 = *(const bf16x8*)&K_[(nt * 16 + l16) * 64 + c0];
      bf16x8 kb1 = *(const bf16x8*)&K_[(nt * 16 + l16) * 64 + c1];
      vb0[nt] = *(const bf16x8*)&V_[(nt * 16 + l16) * 64 + c0];
      vb1[nt] = *(const bf16x8*)&V_[(nt * 16 + l16) * 64 + c1];
      scA[nt] = MFMA16(kb0, qfA0, scA[nt]);
      scA[nt] = MFMA16(kb1, qfA1, scA[nt]);
      scB[nt] = MFMA16(kb0, qfB0, scB[nt]);
      scB[nt] = MFMA16(kb1, qfB1, scB[nt]);
    }
    softpv(vb0, vb1, scA, oA, lsA, qrA, adiag, k0);
    softpv(vb0, vb1, scB, oB, lsB, qrB, false, k0);
  };

  stage(0, 0);
  const int kmax = 2 * qt; // A's diagonal tile index; B diag at kmax+1
  int kt = 0;
  for (; kt < kmax; kt += 2) {
    __syncthreads();
    stage(kt + 1, 1);
    computeAB(0, kt * 64, false);
    __syncthreads();
    stage(kt + 2, 0);
    computeAB(1, (kt + 1) * 64, false);
  }
  // kt == kmax (even), buf0 holds tile kmax
  __syncthreads();
  stage(kmax + 1, 1);
  computeAB(0, kmax * 64, true); // A diag-masked, B full
  __syncthreads();
  { // B diagonal tile (buf1): B only
    const unsigned short* K_ = Ks[1];
    const unsigned short* V_ = Vs[1];
    f32x4 scB[4] = {};
    bf16x8 vb0[4], vb1[4];
#pragma unroll
    for (int nt = 0; nt < 4; nt++) {
      bf16x8 kb0 = *(const bf16x8*)&K_[(nt * 16 + l16) * 64 + c0];
      bf16x8 kb1 = *(const bf16x8*)&K_[(nt * 16 + l16) * 64 + c1];
      vb0[nt] = *(const bf16x8*)&V_[(nt * 16 + l16) * 64 + c0];
      vb1[nt] = *(const bf16x8*)&V_[(nt * 16 + l16) * 64 + c1];
      scB[nt] = MFMA16(kb0, qfB0, scB[nt]);
      scB[nt] = MFMA16(kb1, qfB1, scB[nt]);
    }
    softpv(vb0, vb1, scB, oB, lsB, qrB, true, (kmax + 1) * 64);
  }

  const float ivA = 1.0f / lsA[0], ivB = 1.0f / lsB[0];
  const int b = bh >> 4, h = bh & 15;
  unsigned short* dA = Xat + (size_t)(b * S_LEN + qrA) * DMODEL + h * DHEAD;
  unsigned short* dB = Xat + (size_t)(b * S_LEN + qrB) * DMODEL + h * DHEAD;
#pragma unroll
  for (int nt = 0; nt < 4; nt++) {
    ushort4 wa, wb;
    wa.x = f2b(oA[nt][0] * ivA); wa.y = f2b(oA[nt][1] * ivA);
    wa.z = f2b(oA[nt][2] * ivA); wa.w = f2b(oA[nt][3] * ivA);
    wb.x = f2b(oB[nt][0] * ivB); wb.y = f2b(oB[nt][1] * ivB);
    wb.z = f2b(oB[nt][2] * ivB); wb.w = f2b(oB[nt][3] * ivB);
    *(ushort4*)(dA + nt * 16 + quad * 4) = wa;
    *(ushort4*)(dB + nt * 16 + quad * 4) = wb;
  }
}

extern "C" void kernel_launch(void* const* d_in, const int* in_sizes, int n_in,
                              void* d_out, int out_size, void* d_ws, size_t ws_size,
                              hipStream_t stream) {
  const float* x = (const float*)d_in[0];
  const float* wq = (const float*)d_in[1];
  const float* wk = (const float*)d_in[2];
  const float* wv = (const float*)d_in[3];
  const float* wo = (const float*)d_in[4];
  const int* pos = (const int*)d_in[5];
  float* out = (float*)d_out;
  char* ws = (char*)d_ws;

  const size_t EL_X = (size_t)MROWS * DMODEL; // 8M elements
  const size_t EL_W = (size_t)DMODEL * DMODEL;
  unsigned short* Xb = (unsigned short*)ws; // bf16 activations [M,K]
  unsigned short* Wqkv = Xb + EL_X;         // [3072][1024] stacked q,k,v
  unsigned short* WoT = Wqkv + 3 * EL_W;
  unsigned short* Qr = WoT + EL_W;  // [b,h,s,dh] roped, pre-scaled
  unsigned short* Kr = Qr + EL_X;   // [b,h,s,dh] roped
  unsigned short* Vt = Kr + EL_X;   // [b,h,dh,s]
  unsigned short* Xat = Vt + EL_X;  // [b,s,h,dh] attention output

  PrepArgs pa;
  pa.x = (const float4*)x; pa.xb = Xb;
  pa.n4 = (int)(EL_X / 4);
  pa.cvtBlocks = (int)(EL_X / 4 / 256); // 8192
  pa.s[0] = wq; pa.d[0] = Wqkv;
  pa.s[1] = wk; pa.d[1] = Wqkv + EL_W;
  pa.s[2] = wv; pa.d[2] = Wqkv + 2 * EL_W;
  pa.s[3] = wo; pa.d[3] = WoT;
  prep_kernel<<<pa.cvtBlocks + 1024, 256, 0, stream>>>(pa);

  dim3 gq(24, 64); // N=3072/128, M=8192/128
  gemm_qkv<<<gq, 256, 0, stream>>>(Xb, Wqkv, Qr, Kr, Vt, pos);
  flash_kernel<<<1024, 256, 0, stream>>>(Qr, Kr, Vt, Xat);
  dim3 gg(8, 64);
  gemm_out<<<gg, 256, 0, stream>>>(Xat, WoT, out);
}

// Round 9
// 284.662 us; speedup vs baseline: 1.0267x; 1.0267x over previous
//
#include <hip/hip_runtime.h>
#include <stdint.h>
#include <math.h>

#define S_LEN 2048
#define DMODEL 1024
#define NHEAD 16
#define DHEAD 64
#define BATCH 4
#define MROWS (BATCH * S_LEN) // 8192

typedef __attribute__((ext_vector_type(8))) short bf16x8;
typedef __attribute__((ext_vector_type(4))) float f32x4;

#define MFMA16(a, b, c) __builtin_amdgcn_mfma_f32_16x16x32_bf16(a, b, c, 0, 0, 0)

__device__ __forceinline__ unsigned short f2b(float f) {
  union { float f; unsigned u; } v; v.f = f;
  unsigned u = v.u;
  return (unsigned short)((u + 0x7FFFu + ((u >> 16) & 1u)) >> 16);
}
// pack two f32 -> bf16x2 in ONE VALU op (RNE); replaces 3-op pkrn. lo=a, hi=b.
__device__ __forceinline__ unsigned cvtpk(float a, float b) {
  unsigned r;
  asm("v_cvt_pk_bf16_f32 %0, %1, %2" : "=v"(r) : "v"(a), "v"(b));
  return r;
}

// async global->LDS, 16B per lane; LDS dest = uniform base + lane*16
__device__ __forceinline__ void async16(const void* g, void* l) {
  __builtin_amdgcn_global_load_lds((const __attribute__((address_space(1))) void*)g,
                                   (__attribute__((address_space(3))) void*)l,
                                   16, 0, 0);
}

// ---------------- fused prep: cvt + transpose + RoPE cos/sin table ----------
// Blocks [0,cvtBlocks): f32->bf16 elementwise. [cvtBlocks, +1024): 4x weight
// transpose. [cvtBlocks+1024, +256): RoPE table tab[p][i] = (cos,sin)(p*it_i),
// p in [0,2048), i in [0,32). Same __sinf/__cosf numerics as the old
// in-epilogue computation, hoisted out of gemm_qkv.
// R8 BUG (container-killer): tab was placed PAST Xat+EL_X, beyond the
// workspace high-water mark used by all passing rounds -> OOB writes -> GPU
// fault. R9 fix: tab OVERLAYS Xat (tab written by prep, read by gemm_qkv,
// dead before flash_kernel writes Xat -- same-stream ordering makes it safe).
struct PrepArgs {
  const float4* x; unsigned short* xb; int n4; int cvtBlocks;
  const float* s[4]; unsigned short* d[4];
  float2* tab;
};
__global__ __launch_bounds__(256) void prep_kernel(PrepArgs p) {
  __shared__ float T[64][65];
  const int bid = blockIdx.x;
  const int t = threadIdx.x;
  if (bid < p.cvtBlocks) {
    int i = bid * 256 + t;
    if (i < p.n4) {
      float4 v = p.x[i];
      ushort4 o;
      o.x = f2b(v.x); o.y = f2b(v.y); o.z = f2b(v.z); o.w = f2b(v.w);
      *(ushort4*)(p.xb + 4 * (size_t)i) = o;
    }
    return;
  }
  if (bid >= p.cvtBlocks + 1024) {
    // RoPE table: 256 blocks x 256 threads = 65536 = 2048 pos x 32 freqs
    const float LT = 0.28782313662425572f; // ln(10000)/32
    int idx = (bid - p.cvtBlocks - 1024) * 256 + t;
    int s = idx >> 5, i = idx & 31;
    float a = (float)s * __expf(-(float)i * LT);
    p.tab[idx] = make_float2(__cosf(a), __sinf(a));
    return;
  }
  const int tb = bid - p.cvtBlocks;
  const int z = tb >> 8;
  const int rem = tb & 255;
  const int r0 = (rem >> 4) * 64, c0 = (rem & 15) * 64;
  const float* in = p.s[z];
  unsigned short* out = p.d[z];
  int c = t & 63, rr = t >> 6;
#pragma unroll
  for (int i = 0; i < 16; i++) {
    int r = i * 4 + rr;
    T[r][c] = in[(size_t)(r0 + r) * 1024 + c0 + c];
  }
  __syncthreads();
  int r2 = t & 63, cc = t >> 6;
#pragma unroll
  for (int i = 0; i < 16; i++) {
    int c2 = i * 4 + cc;
    out[(size_t)(c0 + c2) * 1024 + r0 + r2] = f2b(T[r2][c2]);
  }
}

// ---------------- fused QKV GEMM: C[8192,3072] = Xb * Wqkv^T -----------------
// PROVEN 128^2 2-barrier structure (72.8us, 708 TF, MfmaUtil 29).
// R3's 256^2 8-phase port REGRESSED to 92us; needs the exact HK
// barrier/residency placement (m152) -- do not re-attempt naively.
// R8/R9: RoPE sincos (64 trans ops/thread) -> 2 coalesced float2 table loads
// per row-iter (L2-hot 512KB table), trimming the issue-bound epilogue.
__global__ __launch_bounds__(256) void gemm_qkv(const unsigned short* __restrict__ A,
                                                const unsigned short* __restrict__ Bt,
                                                unsigned short* __restrict__ Qr,
                                                unsigned short* __restrict__ Kr,
                                                unsigned short* __restrict__ Vt,
                                                const int* __restrict__ pos,
                                                const float2* __restrict__ tab) {
  constexpr int K = 1024;
  __shared__ unsigned short As[128 * 64];
  __shared__ unsigned short Bs[128 * 64];
  const int bm = blockIdx.y * 128, bn = blockIdx.x * 128;
  const int t = threadIdx.x;
  const int wave = t >> 6, lane = t & 63, quad = lane >> 4, l16 = lane & 15;
  const int wm = (wave >> 1) * 64, wn = (wave & 1) * 64;
  f32x4 acc[4][4] = {};
  const int srow = lane >> 3;
  const int gcol = (((lane & 7) ^ srow)) * 8; // XOR-swizzled source column
  const unsigned short* Ag = A + (size_t)(bm + wave * 32 + srow) * K + gcol;
  const unsigned short* Bg = Bt + (size_t)(bn + wave * 32 + srow) * K + gcol;
  unsigned short* AsW = &As[(wave * 32) * 64];
  unsigned short* BsW = &Bs[(wave * 32) * 64];
  const int rsw = l16 & 7;

  for (int k0 = 0; k0 < K; k0 += 64) {
    __syncthreads();
#pragma unroll
    for (int i = 0; i < 4; i++) {
      async16(Ag + (size_t)(i * 8) * K + k0, AsW + i * 8 * 64);
      async16(Bg + (size_t)(i * 8) * K + k0, BsW + i * 8 * 64);
    }
    __syncthreads();
#pragma unroll
    for (int kk = 0; kk < 2; kk++) {
      const int sl = ((kk * 4 + quad) ^ rsw) << 3;
      bf16x8 af[4], bfr[4];
#pragma unroll
      for (int mt = 0; mt < 4; mt++)
        af[mt] = *(const bf16x8*)&As[(wm + mt * 16 + l16) * 64 + sl];
#pragma unroll
      for (int nt = 0; nt < 4; nt++)
        bfr[nt] = *(const bf16x8*)&Bs[(wn + nt * 16 + l16) * 64 + sl];
#pragma unroll
      for (int mt = 0; mt < 4; mt++)
#pragma unroll
        for (int nt = 0; nt < 4; nt++)
          acc[mt][nt] = MFMA16(af[mt], bfr[nt], acc[mt][nt]);
    }
  }

  const int cb = bn + wn;
  if (cb >= 2048) {
    // V: write directly transposed [b,h,dh,s]
    const int h = (cb - 2048) >> 6;
#pragma unroll
    for (int mt = 0; mt < 4; mt++)
#pragma unroll
      for (int nt = 0; nt < 4; nt++) {
        int row = bm + wm + mt * 16 + quad * 4;
        int b = row >> 11, s = row & (S_LEN - 1);
        int dh = nt * 16 + l16;
        ushort4 w4;
        w4.x = f2b(acc[mt][nt][0]); w4.y = f2b(acc[mt][nt][1]);
        w4.z = f2b(acc[mt][nt][2]); w4.w = f2b(acc[mt][nt][3]);
        *(ushort4*)&Vt[((size_t)(b * NHEAD + h) * DHEAD + dh) * S_LEN + s] = w4;
      }
  } else {
    const bool isQ = cb < 1024;
    unsigned short* dst0 = isQ ? Qr : Kr;
    const float scl = isQ ? 0.18033688011112042f : 1.0f; // 0.125*log2(e) for Q
    const int h = (cb >> 6) & 15;
#pragma unroll
    for (int mt = 0; mt < 4; mt++) {
#pragma unroll
      for (int r = 0; r < 4; r++) {
        int row = bm + wm + mt * 16 + quad * 4 + r;
        int b = row >> 11, s = row & (S_LEN - 1);
        int p = pos[row];
        float2 cs0 = tab[p * 32 + l16];
        float2 cs1 = tab[p * 32 + 16 + l16];
        float x0 = acc[mt][0][r], x1 = acc[mt][1][r];
        float x2 = acc[mt][2][r], x3 = acc[mt][3][r];
        float o0 = (x0 * cs0.x - x2 * cs0.y) * scl;
        float o2 = (x2 * cs0.x + x0 * cs0.y) * scl;
        float o1 = (x1 * cs1.x - x3 * cs1.y) * scl;
        float o3 = (x3 * cs1.x + x1 * cs1.y) * scl;
        unsigned short* dst =
            dst0 + ((size_t)(b * NHEAD + h) * S_LEN + s) * DHEAD;
        dst[0 * 16 + l16] = f2b(o0);
        dst[1 * 16 + l16] = f2b(o1);
        dst[2 * 16 + l16] = f2b(o2);
        dst[3 * 16 + l16] = f2b(o3);
      }
    }
  }
}

// ---------------- out-proj GEMM: out[8192,1024] f32 = Xat * WoT^T -----------
__global__ __launch_bounds__(256) void gemm_out(const unsigned short* __restrict__ A,
                                                const unsigned short* __restrict__ Bt,
                                                float* __restrict__ C) {
  constexpr int K = 1024, N = 1024;
  __shared__ unsigned short As[128 * 64];
  __shared__ unsigned short Bs[128 * 64];
  const int bm = blockIdx.y * 128, bn = blockIdx.x * 128;
  const int t = threadIdx.x;
  const int wave = t >> 6, lane = t & 63, quad = lane >> 4, l16 = lane & 15;
  const int wm = (wave >> 1) * 64, wn = (wave & 1) * 64;
  f32x4 acc[4][4] = {};
  const int srow = lane >> 3;
  const int gcol = (((lane & 7) ^ srow)) * 8;
  const unsigned short* Ag = A + (size_t)(bm + wave * 32 + srow) * K + gcol;
  const unsigned short* Bg = Bt + (size_t)(bn + wave * 32 + srow) * K + gcol;
  unsigned short* AsW = &As[(wave * 32) * 64];
  unsigned short* BsW = &Bs[(wave * 32) * 64];
  const int rsw = l16 & 7;

  for (int k0 = 0; k0 < K; k0 += 64) {
    __syncthreads();
#pragma unroll
    for (int i = 0; i < 4; i++) {
      async16(Ag + (size_t)(i * 8) * K + k0, AsW + i * 8 * 64);
      async16(Bg + (size_t)(i * 8) * K + k0, BsW + i * 8 * 64);
    }
    __syncthreads();
#pragma unroll
    for (int kk = 0; kk < 2; kk++) {
      const int sl = ((kk * 4 + quad) ^ rsw) << 3;
      bf16x8 af[4], bfr[4];
#pragma unroll
      for (int mt = 0; mt < 4; mt++)
        af[mt] = *(const bf16x8*)&As[(wm + mt * 16 + l16) * 64 + sl];
#pragma unroll
      for (int nt = 0; nt < 4; nt++)
        bfr[nt] = *(const bf16x8*)&Bs[(wn + nt * 16 + l16) * 64 + sl];
#pragma unroll
      for (int mt = 0; mt < 4; mt++)
#pragma unroll
        for (int nt = 0; nt < 4; nt++)
          acc[mt][nt] = MFMA16(af[mt], bfr[nt], acc[mt][nt]);
    }
  }
#pragma unroll
  for (int mt = 0; mt < 4; mt++)
#pragma unroll
    for (int nt = 0; nt < 4; nt++)
#pragma unroll
      for (int r = 0; r < 4; r++) {
        int row = bm + wm + mt * 16 + quad * 4 + r;
        int col = bn + wn + nt * 16 + l16;
        C[(size_t)row * N + col] = acc[mt][nt][r];
      }
}

// ---------------- flash attention: 128 q-rows/block (two 64-row halves) -----
// R6 state (best: ~65us). Levers closed: balance (R1/R4), LDS-read trim (R6,
// +1us), occupancy waves/EU=4 (R7: allocator clamps to 64 VGPR + spill),
// raw exp2 builtin (R7: absmax 0.0078 -> 0.0283). Open: VALU-chain trims
// (R5: -7us was the one win).
__global__ __launch_bounds__(256, 3) void flash_kernel(const unsigned short* __restrict__ Qr,
                                                       const unsigned short* __restrict__ Kr,
                                                       const unsigned short* __restrict__ Vt,
                                                       unsigned short* __restrict__ Xat) {
  const int idx = blockIdx.x;        // 0..1023
  const int j = idx >> 6;            // 0..15
  const int c = j & 3, kcl = j >> 2;
  const int qt = (kcl == 0) ? 15 - c : (kcl == 1) ? 7 - c : (kcl == 2) ? 8 + c : c;
  const int bh = idx & 63;
  const unsigned short* Qh = Qr + (size_t)bh * S_LEN * DHEAD;
  const unsigned short* Kh = Kr + (size_t)bh * S_LEN * DHEAD;
  const unsigned short* Vh = Vt + (size_t)bh * DHEAD * S_LEN;
  __shared__ unsigned short Ks[2][64 * 64]; // [kcol][dh], XOR-swizzled slots
  __shared__ unsigned short Vs[2][64 * 64]; // [dh][kcol], XOR-swizzled slots
  __shared__ unsigned short Pt[4][16 * 64]; // per-wave P^T [q][k], swizzled
  const int t = threadIdx.x, wave = t >> 6, lane = t & 63;
  const int quad = lane >> 4, l16 = lane & 15;
  const int srow = lane >> 3;
  const int gcol = (((lane & 7) ^ srow)) * 8;
  const int rsw = l16 & 7;
  const int q0 = qt * 128;
  const int qrA = q0 + wave * 16 + l16;  // half A row
  const int qrB = qrA + 64;              // half B row

  bf16x8 qfA0 = *(const bf16x8*)(Qh + (size_t)qrA * DHEAD + quad * 8);
  bf16x8 qfA1 = *(const bf16x8*)(Qh + (size_t)qrA * DHEAD + 32 + quad * 8);
  bf16x8 qfB0 = *(const bf16x8*)(Qh + (size_t)qrB * DHEAD + quad * 8);
  bf16x8 qfB1 = *(const bf16x8*)(Qh + (size_t)qrB * DHEAD + 32 + quad * 8);

  f32x4 oA[4] = {}, oB[4] = {};
  f32x4 lsA = {}, lsB = {};  // row-sum accumulators (ones-MFMA); lane's q=l16
  bf16x8 onesf;
#pragma unroll
  for (int i = 0; i < 8; i++) onesf[i] = (short)0x3F80; // bf16 1.0
  unsigned short* PtW = &Pt[wave][0];
  const int c0 = (quad ^ rsw) << 3;        // kk=0 frag slot
  const int c1 = ((4 + quad) ^ rsw) << 3;  // kk=1 frag slot
  const int q1b = quad >> 1, qlo4 = (quad & 1) * 4;
  const int pr = l16 * 64;

  auto stage = [&](int kt, int buf) {
    const int k0 = kt * 64;
#pragma unroll
    for (int i = 0; i < 2; i++) {
      async16(Kh + (size_t)(k0 + wave * 16 + i * 8 + srow) * DHEAD + gcol,
              &Ks[buf][(wave * 16 + i * 8) * 64]);
      async16(Vh + (size_t)(wave * 16 + i * 8 + srow) * S_LEN + k0 + gcol,
              &Vs[buf][(wave * 16 + i * 8) * 64]);
    }
  };

  // softmax (no running max: scores bounded) + P^T pack + PV accumulate.
  // V-frags passed in registers (shared across both halves).
  // Row-sum l via ones-MFMA: lane's col = l16 = its q.
  auto softpv = [&](const bf16x8* vb0, const bf16x8* vb1, f32x4* sc, f32x4* o,
                    f32x4& ls, int qr_, bool diag, int k0) {
#pragma unroll
    for (int nt = 0; nt < 4; nt++) {
      float p0, p1, p2, p3;
      if (diag) {
        int kg = k0 + nt * 16 + quad * 4;
        p0 = (kg + 0 > qr_) ? 0.f : exp2f(sc[nt][0]);
        p1 = (kg + 1 > qr_) ? 0.f : exp2f(sc[nt][1]);
        p2 = (kg + 2 > qr_) ? 0.f : exp2f(sc[nt][2]);
        p3 = (kg + 3 > qr_) ? 0.f : exp2f(sc[nt][3]);
      } else {
        p0 = exp2f(sc[nt][0]);
        p1 = exp2f(sc[nt][1]);
        p2 = exp2f(sc[nt][2]);
        p3 = exp2f(sc[nt][3]);
      }
      uint2 w; w.x = cvtpk(p0, p1); w.y = cvtpk(p2, p3);
      const int slot = ((nt * 2 + q1b) ^ rsw) << 3; // nt literal; XOR != dist over +
      *(uint2*)&PtW[pr + slot + qlo4] = w;
    }
#pragma unroll
    for (int kk = 0; kk < 2; kk++) {
      bf16x8 pb = *(const bf16x8*)&PtW[pr + (((kk * 4 + quad) ^ rsw) << 3)];
      ls = MFMA16(onesf, pb, ls);
      const bf16x8* vb = (kk == 0) ? vb0 : vb1; // kk literal under unroll
#pragma unroll
      for (int nt = 0; nt < 4; nt++) o[nt] = MFMA16(vb[nt], pb, o[nt]);
    }
  };

  // both halves against one tile; K-frags AND V-frags read once from LDS
  auto computeAB = [&](int cur, int k0, bool adiag) {
    const unsigned short* K_ = Ks[cur];
    const unsigned short* V_ = Vs[cur];
    f32x4 scA[4] = {}, scB[4] = {};
    bf16x8 vb0[4], vb1[4];
#pragma unroll
    for (int nt = 0; nt < 4; nt++) {
      bf16x8 kb0 = *(const bf16x8*)&K_[(nt * 16 + l16) * 64 + c0];
      bf16x8 kb1 = *(const bf16x8*)&K_[(nt * 16 + l16) * 64 + c1];
      vb0[nt] = *(const bf16x8*)&V_[(nt * 16 + l16) * 64 + c0];
      vb1[nt] = *(const bf16x8*)&V_[(nt * 16 + l16) * 64 + c1];
      scA[nt] = MFMA16(kb0, qfA0, scA[nt]);
      scA[nt] = MFMA16(kb1, qfA1, scA[nt]);
      scB[nt] = MFMA16(kb0, qfB0, scB[nt]);
      scB[nt] = MFMA16(kb1, qfB1, scB[nt]);
    }
    softpv(vb0, vb1, scA, oA, lsA, qrA, adiag, k0);
    softpv(vb0, vb1, scB, oB, lsB, qrB, false, k0);
  };

  stage(0, 0);
  const int kmax = 2 * qt; // A's diagonal tile index; B diag at kmax+1
  int kt = 0;
  for (; kt < kmax; kt += 2) {
    __syncthreads();
    stage(kt + 1, 1);
    computeAB(0, kt * 64, false);
    __syncthreads();
    stage(kt + 2, 0);
    computeAB(1, (kt + 1) * 64, false);
  }
  // kt == kmax (even), buf0 holds tile kmax
  __syncthreads();
  stage(kmax + 1, 1);
  computeAB(0, kmax * 64, true); // A diag-masked, B full
  __syncthreads();
  { // B diagonal tile (buf1): B only
    const unsigned short* K_ = Ks[1];
    const unsigned short* V_ = Vs[1];
    f32x4 scB[4] = {};
    bf16x8 vb0[4], vb1[4];
#pragma unroll
    for (int nt = 0; nt < 4; nt++) {
      bf16x8 kb0 = *(const bf16x8*)&K_[(nt * 16 + l16) * 64 + c0];
      bf16x8 kb1 = *(const bf16x8*)&K_[(nt * 16 + l16) * 64 + c1];
      vb0[nt] = *(const bf16x8*)&V_[(nt * 16 + l16) * 64 + c0];
      vb1[nt] = *(const bf16x8*)&V_[(nt * 16 + l16) * 64 + c1];
      scB[nt] = MFMA16(kb0, qfB0, scB[nt]);
      scB[nt] = MFMA16(kb1, qfB1, scB[nt]);
    }
    softpv(vb0, vb1, scB, oB, lsB, qrB, true, (kmax + 1) * 64);
  }

  const float ivA = 1.0f / lsA[0], ivB = 1.0f / lsB[0];
  const int b = bh >> 4, h = bh & 15;
  unsigned short* dA = Xat + (size_t)(b * S_LEN + qrA) * DMODEL + h * DHEAD;
  unsigned short* dB = Xat + (size_t)(b * S_LEN + qrB) * DMODEL + h * DHEAD;
#pragma unroll
  for (int nt = 0; nt < 4; nt++) {
    ushort4 wa, wb;
    wa.x = f2b(oA[nt][0] * ivA); wa.y = f2b(oA[nt][1] * ivA);
    wa.z = f2b(oA[nt][2] * ivA); wa.w = f2b(oA[nt][3] * ivA);
    wb.x = f2b(oB[nt][0] * ivB); wb.y = f2b(oB[nt][1] * ivB);
    wb.z = f2b(oB[nt][2] * ivB); wb.w = f2b(oB[nt][3] * ivB);
    *(ushort4*)(dA + nt * 16 + quad * 4) = wa;
    *(ushort4*)(dB + nt * 16 + quad * 4) = wb;
  }
}

extern "C" void kernel_launch(void* const* d_in, const int* in_sizes, int n_in,
                              void* d_out, int out_size, void* d_ws, size_t ws_size,
                              hipStream_t stream) {
  const float* x = (const float*)d_in[0];
  const float* wq = (const float*)d_in[1];
  const float* wk = (const float*)d_in[2];
  const float* wv = (const float*)d_in[3];
  const float* wo = (const float*)d_in[4];
  const int* pos = (const int*)d_in[5];
  float* out = (float*)d_out;
  char* ws = (char*)d_ws;

  const size_t EL_X = (size_t)MROWS * DMODEL; // 8M elements
  const size_t EL_W = (size_t)DMODEL * DMODEL;
  unsigned short* Xb = (unsigned short*)ws; // bf16 activations [M,K]
  unsigned short* Wqkv = Xb + EL_X;         // [3072][1024] stacked q,k,v
  unsigned short* WoT = Wqkv + 3 * EL_W;
  unsigned short* Qr = WoT + EL_W;  // [b,h,s,dh] roped, pre-scaled
  unsigned short* Kr = Qr + EL_X;   // [b,h,s,dh] roped
  unsigned short* Vt = Kr + EL_X;   // [b,h,dh,s]
  unsigned short* Xat = Vt + EL_X;  // [b,s,h,dh] attention output
  // RoPE table OVERLAYS Xat (512KB of 16MB): written by prep, read by
  // gemm_qkv, dead before flash_kernel writes Xat. Keeps workspace footprint
  // identical to all passing rounds (R8's tab-past-Xat was OOB -> GPU fault).
  float2* tab = (float2*)Xat;

  PrepArgs pa;
  pa.x = (const float4*)x; pa.xb = Xb;
  pa.n4 = (int)(EL_X / 4);
  pa.cvtBlocks = (int)(EL_X / 4 / 256); // 8192
  pa.s[0] = wq; pa.d[0] = Wqkv;
  pa.s[1] = wk; pa.d[1] = Wqkv + EL_W;
  pa.s[2] = wv; pa.d[2] = Wqkv + 2 * EL_W;
  pa.s[3] = wo; pa.d[3] = WoT;
  pa.tab = tab;
  prep_kernel<<<pa.cvtBlocks + 1024 + 256, 256, 0, stream>>>(pa);

  dim3 gq(24, 64); // N=3072/128, M=8192/128
  gemm_qkv<<<gq, 256, 0, stream>>>(Xb, Wqkv, Qr, Kr, Vt, pos, tab);
  flash_kernel<<<1024, 256, 0, stream>>>(Qr, Kr, Vt, Xat);
  dim3 gg(8, 64);
  gemm_out<<<gg, 256, 0, stream>>>(Xat, WoT, out);
}

// Round 10
// 283.589 us; speedup vs baseline: 1.0306x; 1.0038x over previous
//
#include <hip/hip_runtime.h>
#include <stdint.h>
#include <math.h>

#define S_LEN 2048
#define DMODEL 1024
#define NHEAD 16
#define DHEAD 64
#define BATCH 4
#define MROWS (BATCH * S_LEN) // 8192

typedef __attribute__((ext_vector_type(8))) short bf16x8;
typedef __attribute__((ext_vector_type(4))) float f32x4;

#define MFMA16(a, b, c) __builtin_amdgcn_mfma_f32_16x16x32_bf16(a, b, c, 0, 0, 0)

__device__ __forceinline__ unsigned short f2b(float f) {
  union { float f; unsigned u; } v; v.f = f;
  unsigned u = v.u;
  return (unsigned short)((u + 0x7FFFu + ((u >> 16) & 1u)) >> 16);
}
// pack two f32 -> bf16x2 in ONE VALU op (RNE); replaces 3-op pkrn. lo=a, hi=b.
__device__ __forceinline__ unsigned cvtpk(float a, float b) {
  unsigned r;
  asm("v_cvt_pk_bf16_f32 %0, %1, %2" : "=v"(r) : "v"(a), "v"(b));
  return r;
}

// async global->LDS, 16B per lane; LDS dest = uniform base + lane*16
__device__ __forceinline__ void async16(const void* g, void* l) {
  __builtin_amdgcn_global_load_lds((const __attribute__((address_space(1))) void*)g,
                                   (__attribute__((address_space(3))) void*)l,
                                   16, 0, 0);
}

// ---------------- fused prep: f32->bf16 cvt (Xb) + 4x 1024x1024 transpose ---
// R9 NOTE: RoPE cos/sin table REMOVED (tested R9: gemm_qkv flat, FETCH +6MB,
// total +5us). The epilogue trig runs on the idle transcendental pipe and was
// already hidden under resident blocks' MFMA; tabling it converts free trans
// cycles into real memory traffic. Closed.
struct PrepArgs {
  const float4* x; unsigned short* xb; int n4; int cvtBlocks;
  const float* s[4]; unsigned short* d[4];
};
__global__ __launch_bounds__(256) void prep_kernel(PrepArgs p) {
  __shared__ float T[64][65];
  const int bid = blockIdx.x;
  const int t = threadIdx.x;
  if (bid < p.cvtBlocks) {
    int i = bid * 256 + t;
    if (i < p.n4) {
      float4 v = p.x[i];
      ushort4 o;
      o.x = f2b(v.x); o.y = f2b(v.y); o.z = f2b(v.z); o.w = f2b(v.w);
      *(ushort4*)(p.xb + 4 * (size_t)i) = o;
    }
    return;
  }
  const int tb = bid - p.cvtBlocks;
  const int z = tb >> 8;
  const int rem = tb & 255;
  const int r0 = (rem >> 4) * 64, c0 = (rem & 15) * 64;
  const float* in = p.s[z];
  unsigned short* out = p.d[z];
  int c = t & 63, rr = t >> 6;
#pragma unroll
  for (int i = 0; i < 16; i++) {
    int r = i * 4 + rr;
    T[r][c] = in[(size_t)(r0 + r) * 1024 + c0 + c];
  }
  __syncthreads();
  int r2 = t & 63, cc = t >> 6;
#pragma unroll
  for (int i = 0; i < 16; i++) {
    int c2 = i * 4 + cc;
    out[(size_t)(c0 + c2) * 1024 + r0 + r2] = f2b(T[r2][c2]);
  }
}

// ---------------- fused QKV GEMM: C[8192,3072] = Xb * Wqkv^T -----------------
// PROVEN 128^2 2-barrier structure (72.2-72.8us, 708 TF, MfmaUtil 29).
// Closed levers: 256^2 8-phase port (R3: 92us -- needs exact HK
// barrier/residency placement per m152); RoPE table (R9: trans pipe was idle,
// table adds memory traffic). Remaining gap to the ~900 TF m97-structure
// ceiling is the barrier-drain stall, structural at HIP source level.
__global__ __launch_bounds__(256) void gemm_qkv(const unsigned short* __restrict__ A,
                                                const unsigned short* __restrict__ Bt,
                                                unsigned short* __restrict__ Qr,
                                                unsigned short* __restrict__ Kr,
                                                unsigned short* __restrict__ Vt,
                                                const int* __restrict__ pos) {
  constexpr int K = 1024;
  __shared__ unsigned short As[128 * 64];
  __shared__ unsigned short Bs[128 * 64];
  const int bm = blockIdx.y * 128, bn = blockIdx.x * 128;
  const int t = threadIdx.x;
  const int wave = t >> 6, lane = t & 63, quad = lane >> 4, l16 = lane & 15;
  const int wm = (wave >> 1) * 64, wn = (wave & 1) * 64;
  f32x4 acc[4][4] = {};
  const int srow = lane >> 3;
  const int gcol = (((lane & 7) ^ srow)) * 8; // XOR-swizzled source column
  const unsigned short* Ag = A + (size_t)(bm + wave * 32 + srow) * K + gcol;
  const unsigned short* Bg = Bt + (size_t)(bn + wave * 32 + srow) * K + gcol;
  unsigned short* AsW = &As[(wave * 32) * 64];
  unsigned short* BsW = &Bs[(wave * 32) * 64];
  const int rsw = l16 & 7;

  for (int k0 = 0; k0 < K; k0 += 64) {
    __syncthreads();
#pragma unroll
    for (int i = 0; i < 4; i++) {
      async16(Ag + (size_t)(i * 8) * K + k0, AsW + i * 8 * 64);
      async16(Bg + (size_t)(i * 8) * K + k0, BsW + i * 8 * 64);
    }
    __syncthreads();
#pragma unroll
    for (int kk = 0; kk < 2; kk++) {
      const int sl = ((kk * 4 + quad) ^ rsw) << 3;
      bf16x8 af[4], bfr[4];
#pragma unroll
      for (int mt = 0; mt < 4; mt++)
        af[mt] = *(const bf16x8*)&As[(wm + mt * 16 + l16) * 64 + sl];
#pragma unroll
      for (int nt = 0; nt < 4; nt++)
        bfr[nt] = *(const bf16x8*)&Bs[(wn + nt * 16 + l16) * 64 + sl];
#pragma unroll
      for (int mt = 0; mt < 4; mt++)
#pragma unroll
        for (int nt = 0; nt < 4; nt++)
          acc[mt][nt] = MFMA16(af[mt], bfr[nt], acc[mt][nt]);
    }
  }

  const int cb = bn + wn;
  if (cb >= 2048) {
    // V: write directly transposed [b,h,dh,s]
    const int h = (cb - 2048) >> 6;
#pragma unroll
    for (int mt = 0; mt < 4; mt++)
#pragma unroll
      for (int nt = 0; nt < 4; nt++) {
        int row = bm + wm + mt * 16 + quad * 4;
        int b = row >> 11, s = row & (S_LEN - 1);
        int dh = nt * 16 + l16;
        ushort4 w4;
        w4.x = f2b(acc[mt][nt][0]); w4.y = f2b(acc[mt][nt][1]);
        w4.z = f2b(acc[mt][nt][2]); w4.w = f2b(acc[mt][nt][3]);
        *(ushort4*)&Vt[((size_t)(b * NHEAD + h) * DHEAD + dh) * S_LEN + s] = w4;
      }
  } else {
    const bool isQ = cb < 1024;
    unsigned short* dst0 = isQ ? Qr : Kr;
    const float scl = isQ ? 0.18033688011112042f : 1.0f; // 0.125*log2(e) for Q
    const int h = (cb >> 6) & 15;
    const float LT = 0.28782313662425572f; // ln(10000)/32
    float it0 = __expf(-(float)l16 * LT);
    float it1 = __expf(-(float)(16 + l16) * LT);
#pragma unroll
    for (int mt = 0; mt < 4; mt++) {
#pragma unroll
      for (int r = 0; r < 4; r++) {
        int row = bm + wm + mt * 16 + quad * 4 + r;
        int b = row >> 11, s = row & (S_LEN - 1);
        float p = (float)pos[row];
        // fast HW sin/cos on the (idle) trans pipe: arg<=2047 rad, reduction
        // error ~1e-4 << bf16 storage error. Hidden under MFMA (R9 evidence).
        float a0 = p * it0, a1 = p * it1;
        float sn0 = __sinf(a0), cs0 = __cosf(a0);
        float sn1 = __sinf(a1), cs1 = __cosf(a1);
        float x0 = acc[mt][0][r], x1 = acc[mt][1][r];
        float x2 = acc[mt][2][r], x3 = acc[mt][3][r];
        float o0 = (x0 * cs0 - x2 * sn0) * scl;
        float o2 = (x2 * cs0 + x0 * sn0) * scl;
        float o1 = (x1 * cs1 - x3 * sn1) * scl;
        float o3 = (x3 * cs1 + x1 * sn1) * scl;
        unsigned short* dst =
            dst0 + ((size_t)(b * NHEAD + h) * S_LEN + s) * DHEAD;
        dst[0 * 16 + l16] = f2b(o0);
        dst[1 * 16 + l16] = f2b(o1);
        dst[2 * 16 + l16] = f2b(o2);
        dst[3 * 16 + l16] = f2b(o3);
      }
    }
  }
}

// ---------------- out-proj GEMM: out[8192,1024] f32 = Xat * WoT^T -----------
__global__ __launch_bounds__(256) void gemm_out(const unsigned short* __restrict__ A,
                                                const unsigned short* __restrict__ Bt,
                                                float* __restrict__ C) {
  constexpr int K = 1024, N = 1024;
  __shared__ unsigned short As[128 * 64];
  __shared__ unsigned short Bs[128 * 64];
  const int bm = blockIdx.y * 128, bn = blockIdx.x * 128;
  const int t = threadIdx.x;
  const int wave = t >> 6, lane = t & 63, quad = lane >> 4, l16 = lane & 15;
  const int wm = (wave >> 1) * 64, wn = (wave & 1) * 64;
  f32x4 acc[4][4] = {};
  const int srow = lane >> 3;
  const int gcol = (((lane & 7) ^ srow)) * 8;
  const unsigned short* Ag = A + (size_t)(bm + wave * 32 + srow) * K + gcol;
  const unsigned short* Bg = Bt + (size_t)(bn + wave * 32 + srow) * K + gcol;
  unsigned short* AsW = &As[(wave * 32) * 64];
  unsigned short* BsW = &Bs[(wave * 32) * 64];
  const int rsw = l16 & 7;

  for (int k0 = 0; k0 < K; k0 += 64) {
    __syncthreads();
#pragma unroll
    for (int i = 0; i < 4; i++) {
      async16(Ag + (size_t)(i * 8) * K + k0, AsW + i * 8 * 64);
      async16(Bg + (size_t)(i * 8) * K + k0, BsW + i * 8 * 64);
    }
    __syncthreads();
#pragma unroll
    for (int kk = 0; kk < 2; kk++) {
      const int sl = ((kk * 4 + quad) ^ rsw) << 3;
      bf16x8 af[4], bfr[4];
#pragma unroll
      for (int mt = 0; mt < 4; mt++)
        af[mt] = *(const bf16x8*)&As[(wm + mt * 16 + l16) * 64 + sl];
#pragma unroll
      for (int nt = 0; nt < 4; nt++)
        bfr[nt] = *(const bf16x8*)&Bs[(wn + nt * 16 + l16) * 64 + sl];
#pragma unroll
      for (int mt = 0; mt < 4; mt++)
#pragma unroll
        for (int nt = 0; nt < 4; nt++)
          acc[mt][nt] = MFMA16(af[mt], bfr[nt], acc[mt][nt]);
    }
  }
#pragma unroll
  for (int mt = 0; mt < 4; mt++)
#pragma unroll
    for (int nt = 0; nt < 4; nt++)
#pragma unroll
      for (int r = 0; r < 4; r++) {
        int row = bm + wm + mt * 16 + quad * 4 + r;
        int col = bn + wn + nt * 16 + l16;
        C[(size_t)row * N + col] = acc[mt][nt][r];
      }
}

// ---------------- flash attention: 128 q-rows/block (two 64-row halves) -----
// BEST state (R6, ~65us; session 73 -> 65 via R5 VALU trim + R6 V-frag
// hoist). Closed levers with evidence: work-pairing balance (R1: +44% staging
// cost), qt-permutation balance (R4: identical profile), LDS-read trim beyond
// V-hoist (R6: +1us only), waves/EU=4 (R7: allocator clamps 64 VGPR + spill),
// raw exp2 builtin (R7: absmax 0.0078 -> 0.0283). Kernel is dependent-chain
// stall-bound; further gains need a restructured pipeline (cross-tile QK^T
// overlap), not op trims.
__global__ __launch_bounds__(256, 3) void flash_kernel(const unsigned short* __restrict__ Qr,
                                                       const unsigned short* __restrict__ Kr,
                                                       const unsigned short* __restrict__ Vt,
                                                       unsigned short* __restrict__ Xat) {
  const int idx = blockIdx.x;        // 0..1023
  const int j = idx >> 6;            // 0..15
  const int c = j & 3, kcl = j >> 2;
  const int qt = (kcl == 0) ? 15 - c : (kcl == 1) ? 7 - c : (kcl == 2) ? 8 + c : c;
  const int bh = idx & 63;
  const unsigned short* Qh = Qr + (size_t)bh * S_LEN * DHEAD;
  const unsigned short* Kh = Kr + (size_t)bh * S_LEN * DHEAD;
  const unsigned short* Vh = Vt + (size_t)bh * DHEAD * S_LEN;
  __shared__ unsigned short Ks[2][64 * 64]; // [kcol][dh], XOR-swizzled slots
  __shared__ unsigned short Vs[2][64 * 64]; // [dh][kcol], XOR-swizzled slots
  __shared__ unsigned short Pt[4][16 * 64]; // per-wave P^T [q][k], swizzled
  const int t = threadIdx.x, wave = t >> 6, lane = t & 63;
  const int quad = lane >> 4, l16 = lane & 15;
  const int srow = lane >> 3;
  const int gcol = (((lane & 7) ^ srow)) * 8;
  const int rsw = l16 & 7;
  const int q0 = qt * 128;
  const int qrA = q0 + wave * 16 + l16;  // half A row
  const int qrB = qrA + 64;              // half B row

  bf16x8 qfA0 = *(const bf16x8*)(Qh + (size_t)qrA * DHEAD + quad * 8);
  bf16x8 qfA1 = *(const bf16x8*)(Qh + (size_t)qrA * DHEAD + 32 + quad * 8);
  bf16x8 qfB0 = *(const bf16x8*)(Qh + (size_t)qrB * DHEAD + quad * 8);
  bf16x8 qfB1 = *(const bf16x8*)(Qh + (size_t)qrB * DHEAD + 32 + quad * 8);

  f32x4 oA[4] = {}, oB[4] = {};
  f32x4 lsA = {}, lsB = {};  // row-sum accumulators (ones-MFMA); lane's q=l16
  bf16x8 onesf;
#pragma unroll
  for (int i = 0; i < 8; i++) onesf[i] = (short)0x3F80; // bf16 1.0
  unsigned short* PtW = &Pt[wave][0];
  const int c0 = (quad ^ rsw) << 3;        // kk=0 frag slot
  const int c1 = ((4 + quad) ^ rsw) << 3;  // kk=1 frag slot
  const int q1b = quad >> 1, qlo4 = (quad & 1) * 4;
  const int pr = l16 * 64;

  auto stage = [&](int kt, int buf) {
    const int k0 = kt * 64;
#pragma unroll
    for (int i = 0; i < 2; i++) {
      async16(Kh + (size_t)(k0 + wave * 16 + i * 8 + srow) * DHEAD + gcol,
              &Ks[buf][(wave * 16 + i * 8) * 64]);
      async16(Vh + (size_t)(wave * 16 + i * 8 + srow) * S_LEN + k0 + gcol,
              &Vs[buf][(wave * 16 + i * 8) * 64]);
    }
  };

  // softmax (no running max: scores bounded) + P^T pack + PV accumulate.
  // V-frags passed in registers (shared across both halves).
  // Row-sum l via ones-MFMA: lane's col = l16 = its q.
  auto softpv = [&](const bf16x8* vb0, const bf16x8* vb1, f32x4* sc, f32x4* o,
                    f32x4& ls, int qr_, bool diag, int k0) {
#pragma unroll
    for (int nt = 0; nt < 4; nt++) {
      float p0, p1, p2, p3;
      if (diag) {
        int kg = k0 + nt * 16 + quad * 4;
        p0 = (kg + 0 > qr_) ? 0.f : exp2f(sc[nt][0]);
        p1 = (kg + 1 > qr_) ? 0.f : exp2f(sc[nt][1]);
        p2 = (kg + 2 > qr_) ? 0.f : exp2f(sc[nt][2]);
        p3 = (kg + 3 > qr_) ? 0.f : exp2f(sc[nt][3]);
      } else {
        p0 = exp2f(sc[nt][0]);
        p1 = exp2f(sc[nt][1]);
        p2 = exp2f(sc[nt][2]);
        p3 = exp2f(sc[nt][3]);
      }
      uint2 w; w.x = cvtpk(p0, p1); w.y = cvtpk(p2, p3);
      const int slot = ((nt * 2 + q1b) ^ rsw) << 3; // nt literal; XOR != dist over +
      *(uint2*)&PtW[pr + slot + qlo4] = w;
    }
#pragma unroll
    for (int kk = 0; kk < 2; kk++) {
      bf16x8 pb = *(const bf16x8*)&PtW[pr + (((kk * 4 + quad) ^ rsw) << 3)];
      ls = MFMA16(onesf, pb, ls);
      const bf16x8* vb = (kk == 0) ? vb0 : vb1; // kk literal under unroll
#pragma unroll
      for (int nt = 0; nt < 4; nt++) o[nt] = MFMA16(vb[nt], pb, o[nt]);
    }
  };

  // both halves against one tile; K-frags AND V-frags read once from LDS
  auto computeAB = [&](int cur, int k0, bool adiag) {
    const unsigned short* K_ = Ks[cur];
    const unsigned short* V_ = Vs[cur];
    f32x4 scA[4] = {}, scB[4] = {};
    bf16x8 vb0[4], vb1[4];
#pragma unroll
    for (int nt = 0; nt < 4; nt++) {
      bf16x8 kb0 = *(const bf16x8*)&K_[(nt * 16 + l16) * 64 + c0];
      bf16x8 kb1 = *(const bf16x8*)&K_[(nt * 16 + l16) * 64 + c1];
      vb0[nt] = *(const bf16x8*)&V_[(nt * 16 + l16) * 64 + c0];
      vb1[nt] = *(const bf16x8*)&V_[(nt * 16 + l16) * 64 + c1];
      scA[nt] = MFMA16(kb0, qfA0, scA[nt]);
      scA[nt] = MFMA16(kb1, qfA1, scA[nt]);
      scB[nt] = MFMA16(kb0, qfB0, scB[nt]);
      scB[nt] = MFMA16(kb1, qfB1, scB[nt]);
    }
    softpv(vb0, vb1, scA, oA, lsA, qrA, adiag, k0);
    softpv(vb0, vb1, scB, oB, lsB, qrB, false, k0);
  };

  stage(0, 0);
  const int kmax = 2 * qt; // A's diagonal tile index; B diag at kmax+1
  int kt = 0;
  for (; kt < kmax; kt += 2) {
    __syncthreads();
    stage(kt + 1, 1);
    computeAB(0, kt * 64, false);
    __syncthreads();
    stage(kt + 2, 0);
    computeAB(1, (kt + 1) * 64, false);
  }
  // kt == kmax (even), buf0 holds tile kmax
  __syncthreads();
  stage(kmax + 1, 1);
  computeAB(0, kmax * 64, true); // A diag-masked, B full
  __syncthreads();
  { // B diagonal tile (buf1): B only
    const unsigned short* K_ = Ks[1];
    const unsigned short* V_ = Vs[1];
    f32x4 scB[4] = {};
    bf16x8 vb0[4], vb1[4];
#pragma unroll
    for (int nt = 0; nt < 4; nt++) {
      bf16x8 kb0 = *(const bf16x8*)&K_[(nt * 16 + l16) * 64 + c0];
      bf16x8 kb1 = *(const bf16x8*)&K_[(nt * 16 + l16) * 64 + c1];
      vb0[nt] = *(const bf16x8*)&V_[(nt * 16 + l16) * 64 + c0];
      vb1[nt] = *(const bf16x8*)&V_[(nt * 16 + l16) * 64 + c1];
      scB[nt] = MFMA16(kb0, qfB0, scB[nt]);
      scB[nt] = MFMA16(kb1, qfB1, scB[nt]);
    }
    softpv(vb0, vb1, scB, oB, lsB, qrB, true, (kmax + 1) * 64);
  }

  const float ivA = 1.0f / lsA[0], ivB = 1.0f / lsB[0];
  const int b = bh >> 4, h = bh & 15;
  unsigned short* dA = Xat + (size_t)(b * S_LEN + qrA) * DMODEL + h * DHEAD;
  unsigned short* dB = Xat + (size_t)(b * S_LEN + qrB) * DMODEL + h * DHEAD;
#pragma unroll
  for (int nt = 0; nt < 4; nt++) {
    ushort4 wa, wb;
    wa.x = f2b(oA[nt][0] * ivA); wa.y = f2b(oA[nt][1] * ivA);
    wa.z = f2b(oA[nt][2] * ivA); wa.w = f2b(oA[nt][3] * ivA);
    wb.x = f2b(oB[nt][0] * ivB); wb.y = f2b(oB[nt][1] * ivB);
    wb.z = f2b(oB[nt][2] * ivB); wb.w = f2b(oB[nt][3] * ivB);
    *(ushort4*)(dA + nt * 16 + quad * 4) = wa;
    *(ushort4*)(dB + nt * 16 + quad * 4) = wb;
  }
}

extern "C" void kernel_launch(void* const* d_in, const int* in_sizes, int n_in,
                              void* d_out, int out_size, void* d_ws, size_t ws_size,
                              hipStream_t stream) {
  const float* x = (const float*)d_in[0];
  const float* wq = (const float*)d_in[1];
  const float* wk = (const float*)d_in[2];
  const float* wv = (const float*)d_in[3];
  const float* wo = (const float*)d_in[4];
  const int* pos = (const int*)d_in[5];
  float* out = (float*)d_out;
  char* ws = (char*)d_ws;

  const size_t EL_X = (size_t)MROWS * DMODEL; // 8M elements
  const size_t EL_W = (size_t)DMODEL * DMODEL;
  unsigned short* Xb = (unsigned short*)ws; // bf16 activations [M,K]
  unsigned short* Wqkv = Xb + EL_X;         // [3072][1024] stacked q,k,v
  unsigned short* WoT = Wqkv + 3 * EL_W;
  unsigned short* Qr = WoT + EL_W;  // [b,h,s,dh] roped, pre-scaled
  unsigned short* Kr = Qr + EL_X;   // [b,h,s,dh] roped
  unsigned short* Vt = Kr + EL_X;   // [b,h,dh,s]
  unsigned short* Xat = Vt + EL_X;  // [b,s,h,dh] attention output

  PrepArgs pa;
  pa.x = (const float4*)x; pa.xb = Xb;
  pa.n4 = (int)(EL_X / 4);
  pa.cvtBlocks = (int)(EL_X / 4 / 256); // 8192
  pa.s[0] = wq; pa.d[0] = Wqkv;
  pa.s[1] = wk; pa.d[1] = Wqkv + EL_W;
  pa.s[2] = wv; pa.d[2] = Wqkv + 2 * EL_W;
  pa.s[3] = wo; pa.d[3] = WoT;
  prep_kernel<<<pa.cvtBlocks + 1024, 256, 0, stream>>>(pa);

  dim3 gq(24, 64); // N=3072/128, M=8192/128
  gemm_qkv<<<gq, 256, 0, stream>>>(Xb, Wqkv, Qr, Kr, Vt, pos);
  flash_kernel<<<1024, 256, 0, stream>>>(Qr, Kr, Vt, Xat);
  dim3 gg(8, 64);
  gemm_out<<<gg, 256, 0, stream>>>(Xat, WoT, out);
}